// Round 6
// baseline (29.352 us; speedup 1.0000x reference)
//
#include <hip/hip_runtime.h>
#include <hip/hip_bf16.h>

// APELoss via moment-corrected histogram, single fused kernel + 8B memset.
//
// Grid = NB hist blocks + NEVAL eval blocks (264 total <= 1 block/CU -> all
// co-resident, polling is deadlock-free).
//  - hist blocks: per-block histogram segment of a bg slice (LDS int count +
//    2^28 fixed-point first moment), per-block bg max. Publish via agent-scope
//    (sc0 sc1, LLC-direct) stores, s_waitcnt vmcnt(0), then relaxed agent
//    atomicAdd(hist_ctr). NO __threadfence (R4: per-block agent fence = L2
//    writeback ~15us).
//  - eval blocks: fg-fg exact pairwise FIRST (overlaps hist build; results
//    stay in LDS -- no global round-trip), then poll hist_ctr == NB, merge
//    the NB segments with agent-scope LOADS (no kernel-boundary acquire
//    anymore; per-XCD L2s may hold stale lines from a previous graph replay),
//    evaluate 4 rows over B_BINS bins with first-order Taylor correction,
//    fold to a per-block (sper,sval) partial, publish agent-scope +
//    vmcnt(0) + atomicAdd(fin_ctr); block seeing NEVAL-1 reduces partials
//    (fixed order -> deterministic) and writes the scalar.
//
// Math (log2 domain): dl = KC*(c - f), mask dl > -KC else -inf.
//   u = 2^dl, o = 1+u, rr = rcp(o): sigmoid = 1-rr, softplus/ln2 = log2(o)
//   d(sigmoid)/dv = LAMB*(1-rr)*rr ; d(softplus/ln2)/dv = KC*(1-rr)
// valid_i = (bg_max > f_i - 1) || fg_pos_count_i > 0.

#define APE_LAMB 4.0f
#define APE_KC   5.770780163555856f   // LAMB * log2(e)
#define APE_LN2  0.6931471805599453f
#define NINF     (-__builtin_inff())

__device__ __forceinline__ float exp2g(float x) { return __builtin_amdgcn_exp2f(x); }
__device__ __forceinline__ float log2g(float x) { return __builtin_amdgcn_logf(x); }
__device__ __forceinline__ float rcpg(float x)  { return __builtin_amdgcn_rcpf(x); }

constexpr int   B_BINS  = 1024;
constexpr int   NB      = 8;      // histogram segment blocks
constexpr int   TPB     = 256;
constexpr float BIN_LO  = -5.12f;
constexpr float BIN_DL  = 0.01f;
constexpr float BIN_INV = 100.0f;
constexpr float M1SCALE = 268435456.0f;             // 2^28
constexpr float M1INV   = 3.725290298461914e-09f;   // 2^-28
constexpr int   ROWS    = 4;      // fg rows per eval block

#define ST_AGENT(p, v) __hip_atomic_store((p), (v), __ATOMIC_RELAXED, __HIP_MEMORY_SCOPE_AGENT)
#define LD_AGENT(p)    __hip_atomic_load((p), __ATOMIC_RELAXED, __HIP_MEMORY_SCOPE_AGENT)

__global__ __launch_bounds__(TPB) void ape_fused(
    const float* __restrict__ logits, const float* __restrict__ ious,
    int F, int M, int chunkH, int NEVAL,
    float* __restrict__ gC, float* __restrict__ gM, float* __restrict__ bmaxA,
    float* __restrict__ pp, float* __restrict__ pv,
    int* __restrict__ ctr, float* __restrict__ out)
{
    const int tid  = threadIdx.x;
    const int lane = tid & 63, wid = tid >> 6;

    if ((int)blockIdx.x < NB) {
        // ================= hist block =================
        __shared__ int hc[B_BINS];
        __shared__ int hm[B_BINS];
        for (int b = tid; b < B_BINS; b += TPB) { hc[b] = 0; hm[b] = 0; }
        __syncthreads();

        const float* bg = logits + F;
        const int start = (int)blockIdx.x * chunkH;
        const int end   = min(start + chunkH, M);
        float bmax = NINF;

        for (int j = start + tid * 4; j < end; j += TPB * 4) {
            float v[4];
            if (j + 4 <= end) {
                float4 q = *reinterpret_cast<const float4*>(bg + j);
                v[0] = q.x; v[1] = q.y; v[2] = q.z; v[3] = q.w;
            } else {
#pragma unroll
                for (int k = 0; k < 4; ++k) v[k] = (j + k < end) ? bg[j + k] : NINF;
            }
#pragma unroll
            for (int k = 0; k < 4; ++k) {
                if (j + k >= end) continue;
                float x = v[k];
                bmax = fmaxf(bmax, x);
                int b = (int)((x - BIN_LO) * BIN_INV);
                b = min(max(b, 0), B_BINS - 1);
                float c = fmaf((float)b, BIN_DL, BIN_LO + 0.5f * BIN_DL);
                int q = __float2int_rn((x - c) * M1SCALE);
                atomicAdd(&hc[b], 1);
                atomicAdd(&hm[b], q);
            }
        }
        __syncthreads();
        const int base = (int)blockIdx.x * B_BINS;
        for (int b = tid; b < B_BINS; b += TPB) {
            ST_AGENT(&gC[base + b], (float)hc[b]);
            ST_AGENT(&gM[base + b], (float)hm[b] * M1INV);   // logit units
        }
        __shared__ float rm[4];
        for (int off = 32; off > 0; off >>= 1) bmax = fmaxf(bmax, __shfl_down(bmax, off));
        if (lane == 0) rm[wid] = bmax;
        __syncthreads();
        if (tid == 0)
            ST_AGENT(&bmaxA[blockIdx.x],
                     fmaxf(fmaxf(rm[0], rm[1]), fmaxf(rm[2], rm[3])));
        asm volatile("s_waitcnt vmcnt(0)" ::: "memory");  // all stores at LLC
        __syncthreads();
        if (tid == 0)
            __hip_atomic_fetch_add(&ctr[0], 1, __ATOMIC_RELAXED,
                                   __HIP_MEMORY_SCOPE_AGENT);
        return;
    }

    // ================= eval block =================
    const int e  = (int)blockIdx.x - NB;
    const int i0 = e * ROWS;

    float fKC[ROWS], ioui[ROWS];
#pragma unroll
    for (int r = 0; r < ROWS; ++r) {
        int i = i0 + r;
        fKC[r]  = (i < F) ? logits[i] * APE_KC : __builtin_inff();
        ioui[r] = (i < F) ? ious[i] : 0.f;
    }

    // ---- fg-fg exact pairwise (overlaps hist build) ----
    float fdist[ROWS], frank[ROWS], fcnt[ROWS];
#pragma unroll
    for (int r = 0; r < ROWS; ++r) { fdist[r]=0.f; frank[r]=0.f; fcnt[r]=0.f; }

    for (int j = tid; j < F; j += TPB) {
        float fjl  = logits[j] * APE_KC;
        float iouj = ious[j];
#pragma unroll
        for (int r = 0; r < ROWS; ++r) {
            float dl = fjl - fKC[r];
            bool above = dl > -APE_KC;
            float dm = above ? dl : NINF;
            float u  = exp2g(dm);
            float o  = 1.0f + u;
            float sig = 1.0f - rcpg(o);
            float spl = log2g(o);
            bool pos = iouj < ioui[r];
            frank[r] += sig;
            fdist[r] += pos ? spl : 0.f;
            fcnt[r]  += (above && pos) ? 1.f : 0.f;
        }
    }
    __shared__ float redf[4][ROWS * 3];
    __shared__ float fg3[ROWS * 3];     // per-row fg-fg results: rank,dist,cnt
#pragma unroll
    for (int r = 0; r < ROWS; ++r) {
        float a = frank[r], d = fdist[r], c = fcnt[r];
        for (int off = 32; off > 0; off >>= 1) {
            a += __shfl_down(a, off);
            d += __shfl_down(d, off);
            c += __shfl_down(c, off);
        }
        if (lane == 0) { redf[wid][r*3+0]=a; redf[wid][r*3+1]=d; redf[wid][r*3+2]=c; }
    }
    __syncthreads();
    if (tid < ROWS * 3)
        fg3[tid] = redf[0][tid] + redf[1][tid] + redf[2][tid] + redf[3][tid];

    // ---- wait for histogram segments ----
    if (tid == 0) {
        while (LD_AGENT(&ctr[0]) < NB) __builtin_amdgcn_s_sleep(8);
    }
    __syncthreads();   // barrier (memory-clobber) orders merge loads after poll

    // ---- merge NB segments into LDS (fixed order -> deterministic) ----
    __shared__ float2 h[B_BINS];
    for (int b = tid; b < B_BINS; b += TPB) {
        float c = 0.f, m = 0.f;
#pragma unroll
        for (int s = 0; s < NB; ++s) {
            c += LD_AGENT(&gC[s * B_BINS + b]);   // agent loads: per-XCD L2 may
            m += LD_AGENT(&gM[s * B_BINS + b]);   // hold stale lines (replays)
        }
        h[b] = make_float2(c, m);
    }
    __syncthreads();

    // ---- eval 4 rows over the histogram ----
    float rk[ROWS], dt[ROWS];
#pragma unroll
    for (int r = 0; r < ROWS; ++r) { rk[r] = 0.f; dt[r] = 0.f; }

    for (int it = 0; it < B_BINS; it += TPB) {
        const int b = it + tid;
        float2 cm = h[b];
        float cKC  = fmaf((float)b, BIN_DL * APE_KC, (BIN_LO + 0.5f * BIN_DL) * APE_KC);
        float m1x4 = cm.y * APE_LAMB;
        float m1kc = cm.y * APE_KC;
#pragma unroll
        for (int r = 0; r < ROWS; ++r) {
            float dl = cKC - fKC[r];
            float dm = (dl > -APE_KC) ? dl : NINF;
            float u  = exp2g(dm);
            float o  = 1.0f + u;
            float rr = rcpg(o);
            float lg = log2g(o);
            float s  = 1.0f - rr;
            rk[r] = fmaf(cm.x, s,  rk[r]);
            rk[r] = fmaf(m1x4, s * rr, rk[r]);
            dt[r] = fmaf(cm.x, lg, dt[r]);
            dt[r] = fmaf(m1kc, s,  dt[r]);
        }
    }

    __shared__ float red[4][ROWS * 2];
#pragma unroll
    for (int r = 0; r < ROWS; ++r) {
        float a = rk[r], d = dt[r];
        for (int off = 32; off > 0; off >>= 1) {
            a += __shfl_down(a, off);
            d += __shfl_down(d, off);
        }
        if (lane == 0) { red[wid][r*2+0] = a; red[wid][r*2+1] = d; }
    }
    __syncthreads();

    // ---- per-block partial, fence-free publish, last-block finalize ----
    __shared__ int lastFlag;
    if (tid == 0) {
        float gmax = NINF;
#pragma unroll
        for (int k = 0; k < NB; ++k) gmax = fmaxf(gmax, LD_AGENT(&bmaxA[k]));
        float sper = 0.f, sval = 0.f;
#pragma unroll
        for (int r = 0; r < ROWS; ++r) {
            int i = i0 + r;
            if (i < F) {
                float rowRank = red[0][r*2+0] + red[1][r*2+0] + red[2][r*2+0] + red[3][r*2+0];
                float rowDist = red[0][r*2+1] + red[1][r*2+1] + red[2][r*2+1] + red[3][r*2+1];
                float rkv = rowRank + fg3[r*3+0];
                float dtv = (rowDist + fg3[r*3+1]) * APE_LN2;
                bool valid = (gmax > logits[i] - 1.0f) || (fg3[r*3+2] > 0.f);
                if (valid) {
                    sper += dtv * ious[i] / rkv;
                    sval += 1.f;
                }
            }
        }
        ST_AGENT(&pp[e], sper);
        ST_AGENT(&pv[e], sval);
        asm volatile("s_waitcnt vmcnt(0)" ::: "memory");  // partials at LLC
        int old = __hip_atomic_fetch_add(&ctr[1], 1, __ATOMIC_RELAXED,
                                         __HIP_MEMORY_SCOPE_AGENT);
        lastFlag = (old == NEVAL - 1) ? 1 : 0;
    }
    __syncthreads();
    if (!lastFlag) return;

    float sp = 0.f, sv = 0.f;
    for (int k = tid; k < NEVAL; k += TPB) {
        sp += LD_AGENT(&pp[k]);
        sv += LD_AGENT(&pv[k]);
    }
    __shared__ float rp[4], rv[4];
    for (int off = 32; off > 0; off >>= 1) {
        sp += __shfl_down(sp, off);
        sv += __shfl_down(sv, off);
    }
    if (lane == 0) { rp[wid] = sp; rv[wid] = sv; }
    __syncthreads();
    if (tid == 0) {
        float p = rp[0] + rp[1] + rp[2] + rp[3];
        float v = rv[0] + rv[1] + rv[2] + rv[3];
        ST_AGENT(&out[0], p / fmaxf(v, 1.f) / APE_LAMB);
    }
}

extern "C" void kernel_launch(void* const* d_in, const int* in_sizes, int n_in,
                              void* d_out, int out_size, void* d_ws, size_t ws_size,
                              hipStream_t stream) {
    const float* logits = (const float*)d_in[0];
    const float* ious   = (const float*)d_in[2];
    const int N = in_sizes[0];
    const int F = in_sizes[2];
    const int M = N - F;

    const int NEVAL = (F + ROWS - 1) / ROWS;

    float* ws    = (float*)d_ws;
    float* gC    = ws;                       // [NB][B_BINS]
    float* gM    = gC + NB * B_BINS;         // [NB][B_BINS]
    float* bmaxA = gM + NB * B_BINS;         // [NB]
    float* pp    = bmaxA + NB;               // [NEVAL]
    float* pv    = pp + NEVAL;               // [NEVAL]
    int*   ctr   = (int*)(pv + NEVAL);       // [2] hist_done, fin_done

    int chunkH = ((M + NB - 1) / NB + 3) & ~3;
    if (chunkH < 4) chunkH = 4;

    hipMemsetAsync(ctr, 0, 2 * sizeof(int), stream);
    ape_fused<<<NB + NEVAL, TPB, 0, stream>>>(logits, ious, F, M, chunkH, NEVAL,
                                              gC, gM, bmaxA, pp, pv, ctr,
                                              (float*)d_out);
}

// Round 7
// 21.054 us; speedup vs baseline: 1.3941x; 1.3941x over previous
//
#include <hip/hip_runtime.h>
#include <hip/hip_bf16.h>

// APELoss via moment-corrected histogram, 2 dispatches (R5 structure — fused
// single-kernel polling was SLOWER, R6: within-graph kernel boundaries are
// nearly free, software polling + uncached agent loads are not).
//
// K1 (NB hist blocks + F/4 fg-fg blocks):
//   - hist blocks: per-block float2 histogram segment (count, first moment) of
//     a bg slice (LDS int count + 2^28 fixed-point moment; no global atomics,
//     nothing to zero) + per-block bg max. Block 0 zeroes K2's counter.
//   - fg-fg blocks: exact F x F part (dist2/rank2/cnt2 per row).
// K2 (EB = F/4 eval blocks): merge NB float2 segments into LDS (fixed order ->
//   deterministic; visibility via kernel boundary), evaluate 4 rows over
//   B_BINS bins with first-order Taylor, fold with fg-fg partials + validity
//   into a per-block (sper,sval) partial. Publish partial with agent-scope
//   (sc0 sc1, LLC-direct) stores + s_waitcnt vmcnt(0) + relaxed agent
//   atomicAdd (NO __threadfence -- R4: per-block agent fence = L2 writeback,
//   ~15us); block seeing EB-1 reduces partials in fixed order, writes scalar.
//
// Math (log2 domain): dl = KC*(c - f), mask dl > -KC else -inf.
//   u = 2^dl, o = 1+u, rr = rcp(o): sigmoid = 1-rr, softplus/ln2 = log2(o)
//   d(sigmoid)/dv = LAMB*(1-rr)*rr ; d(softplus/ln2)/dv = KC*(1-rr)
// valid_i = (bg_max > f_i - 1) || fg_pos_count_i > 0.

#define APE_LAMB 4.0f
#define APE_KC   5.770780163555856f   // LAMB * log2(e)
#define APE_LN2  0.6931471805599453f
#define NINF     (-__builtin_inff())

__device__ __forceinline__ float exp2g(float x) { return __builtin_amdgcn_exp2f(x); }
__device__ __forceinline__ float log2g(float x) { return __builtin_amdgcn_logf(x); }
__device__ __forceinline__ float rcpg(float x)  { return __builtin_amdgcn_rcpf(x); }

constexpr int   B_BINS  = 1024;
constexpr int   NB      = 16;     // histogram segment blocks (16: halves K1 hist span)
constexpr int   TPB     = 256;
constexpr float BIN_LO  = -5.12f;
constexpr float BIN_DL  = 0.01f;
constexpr float BIN_INV = 100.0f;
constexpr float M1SCALE = 268435456.0f;             // 2^28
constexpr float M1INV   = 3.725290298461914e-09f;   // 2^-28
constexpr int   ROWS_E  = 4;      // fg rows per eval block
constexpr int   ROWS_B  = 4;      // fg rows per fg-fg block

#define ST_AGENT(p, v) __hip_atomic_store((p), (v), __ATOMIC_RELAXED, __HIP_MEMORY_SCOPE_AGENT)
#define LD_AGENT(p)    __hip_atomic_load((p), __ATOMIC_RELAXED, __HIP_MEMORY_SCOPE_AGENT)

// ---------------- K1: hist segments + bg max + fg-fg + ctr reset ------------
__global__ __launch_bounds__(TPB) void ape_phase1(
    const float* __restrict__ logits, const float* __restrict__ ious,
    int F, int M, int chunkH,
    float2* __restrict__ gH, float* __restrict__ bmaxA,
    float* __restrict__ dist2, float* __restrict__ rank2, float* __restrict__ cnt2,
    int* __restrict__ ctr)
{
    const int tid  = threadIdx.x;
    const int lane = tid & 63, wid = tid >> 6;

    if (blockIdx.x == 0 && tid == 0) *ctr = 0;   // visible to K2 via kernel boundary

    if ((int)blockIdx.x < NB) {
        // ---- histogram of one bg slice ----
        __shared__ int hc[B_BINS];
        __shared__ int hm[B_BINS];
        for (int b = tid; b < B_BINS; b += TPB) { hc[b] = 0; hm[b] = 0; }
        __syncthreads();

        const float* bg = logits + F;
        const int start = (int)blockIdx.x * chunkH;
        const int end   = min(start + chunkH, M);
        float bmax = NINF;

        for (int j = start + tid * 4; j < end; j += TPB * 4) {
            float v[4];
            if (j + 4 <= end) {
                float4 q = *reinterpret_cast<const float4*>(bg + j);
                v[0] = q.x; v[1] = q.y; v[2] = q.z; v[3] = q.w;
            } else {
#pragma unroll
                for (int k = 0; k < 4; ++k) v[k] = (j + k < end) ? bg[j + k] : NINF;
            }
#pragma unroll
            for (int k = 0; k < 4; ++k) {
                if (j + k >= end) continue;
                float x = v[k];
                bmax = fmaxf(bmax, x);
                int b = (int)((x - BIN_LO) * BIN_INV);
                b = min(max(b, 0), B_BINS - 1);
                float c = fmaf((float)b, BIN_DL, BIN_LO + 0.5f * BIN_DL);
                int q = __float2int_rn((x - c) * M1SCALE);
                atomicAdd(&hc[b], 1);
                atomicAdd(&hm[b], q);
            }
        }
        __syncthreads();
        const int base = (int)blockIdx.x * B_BINS;
        for (int b = tid; b < B_BINS; b += TPB)
            gH[base + b] = make_float2((float)hc[b], (float)hm[b] * M1INV);

        __shared__ float rm[4];
        for (int off = 32; off > 0; off >>= 1) bmax = fmaxf(bmax, __shfl_down(bmax, off));
        if (lane == 0) rm[wid] = bmax;
        __syncthreads();
        if (tid == 0)
            bmaxA[blockIdx.x] = fmaxf(fmaxf(rm[0], rm[1]), fmaxf(rm[2], rm[3]));
    } else {
        // ---- fg-fg exact pairwise ----
        const int i0 = ((int)blockIdx.x - NB) * ROWS_B;
        float fgl[ROWS_B], ioui[ROWS_B];
#pragma unroll
        for (int r = 0; r < ROWS_B; ++r) {
            int i = i0 + r;
            fgl[r]  = (i < F) ? logits[i] * APE_KC : __builtin_inff();
            ioui[r] = (i < F) ? ious[i] : 0.f;
        }
        float dist[ROWS_B], rank[ROWS_B], cnt[ROWS_B];
#pragma unroll
        for (int r = 0; r < ROWS_B; ++r) { dist[r]=0.f; rank[r]=0.f; cnt[r]=0.f; }

        for (int j = tid; j < F; j += TPB) {
            float fjl  = logits[j] * APE_KC;
            float iouj = ious[j];
#pragma unroll
            for (int r = 0; r < ROWS_B; ++r) {
                float dl = fjl - fgl[r];
                bool above = dl > -APE_KC;
                float dm = above ? dl : NINF;
                float u  = exp2g(dm);
                float o  = 1.0f + u;
                float sig = 1.0f - rcpg(o);
                float spl = log2g(o);
                bool pos = iouj < ioui[r];
                rank[r] += sig;
                dist[r] += pos ? spl : 0.f;
                cnt[r]  += (above && pos) ? 1.f : 0.f;
            }
        }
        __shared__ float redf[4][ROWS_B * 3];
#pragma unroll
        for (int r = 0; r < ROWS_B; ++r) {
            float d = dist[r], a = rank[r], c = cnt[r];
            for (int off = 32; off > 0; off >>= 1) {
                d += __shfl_down(d, off);
                a += __shfl_down(a, off);
                c += __shfl_down(c, off);
            }
            if (lane == 0) { redf[wid][r*3+0]=d; redf[wid][r*3+1]=a; redf[wid][r*3+2]=c; }
        }
        __syncthreads();
        if (tid < ROWS_B * 3) {
            float sum = redf[0][tid] + redf[1][tid] + redf[2][tid] + redf[3][tid];
            int r = tid / 3, q = tid % 3;
            int i = i0 + r;
            if (i < F) {
                if      (q == 0) dist2[i] = sum;
                else if (q == 1) rank2[i] = sum;
                else             cnt2[i]  = sum;
            }
        }
    }
}

// ---------------- K2: merge + eval + per-block partial + last-block final ---
__global__ __launch_bounds__(TPB) void ape_phase2(
    const float* __restrict__ logits, const float* __restrict__ ious, int F, int EB,
    const float2* __restrict__ gH, const float* __restrict__ bmaxA,
    const float* __restrict__ dist2, const float* __restrict__ rank2,
    const float* __restrict__ cnt2,
    float* __restrict__ pp, float* __restrict__ pv,
    int* __restrict__ ctr, float* __restrict__ out)
{
    const int tid  = threadIdx.x;
    const int lane = tid & 63, wid = tid >> 6;

    // merge NB float2 segments into LDS (fixed order -> deterministic)
    __shared__ float2 h[B_BINS];
    for (int b = tid; b < B_BINS; b += TPB) {
        float c = 0.f, m = 0.f;
#pragma unroll
        for (int s = 0; s < NB; ++s) {
            float2 cm = gH[s * B_BINS + b];
            c += cm.x;
            m += cm.y;
        }
        h[b] = make_float2(c, m);
    }

    const int i0 = (int)blockIdx.x * ROWS_E;
    float fKC[ROWS_E];
#pragma unroll
    for (int r = 0; r < ROWS_E; ++r) {
        int i = i0 + r;
        fKC[r] = (i < F) ? logits[i] * APE_KC : __builtin_inff();
    }
    __syncthreads();

    float rk[ROWS_E], dt[ROWS_E];
#pragma unroll
    for (int r = 0; r < ROWS_E; ++r) { rk[r] = 0.f; dt[r] = 0.f; }

    for (int it = 0; it < B_BINS; it += TPB) {
        const int b = it + tid;
        float2 cm = h[b];
        float cKC  = fmaf((float)b, BIN_DL * APE_KC, (BIN_LO + 0.5f * BIN_DL) * APE_KC);
        float m1x4 = cm.y * APE_LAMB;
        float m1kc = cm.y * APE_KC;
#pragma unroll
        for (int r = 0; r < ROWS_E; ++r) {
            float dl = cKC - fKC[r];
            float dm = (dl > -APE_KC) ? dl : NINF;
            float u  = exp2g(dm);
            float o  = 1.0f + u;
            float rr = rcpg(o);
            float lg = log2g(o);
            float s  = 1.0f - rr;
            rk[r] = fmaf(cm.x, s,  rk[r]);
            rk[r] = fmaf(m1x4, s * rr, rk[r]);
            dt[r] = fmaf(cm.x, lg, dt[r]);
            dt[r] = fmaf(m1kc, s,  dt[r]);
        }
    }

    __shared__ float red[4][ROWS_E * 2];
#pragma unroll
    for (int r = 0; r < ROWS_E; ++r) {
        float a = rk[r], d = dt[r];
        for (int off = 32; off > 0; off >>= 1) {
            a += __shfl_down(a, off);
            d += __shfl_down(d, off);
        }
        if (lane == 0) { red[wid][r*2+0] = a; red[wid][r*2+1] = d; }
    }
    __syncthreads();

    // per-block partial of the final sum, published fence-free
    __shared__ int lastFlag;
    if (tid == 0) {
        float gmax = NINF;
#pragma unroll
        for (int k = 0; k < NB; ++k) gmax = fmaxf(gmax, bmaxA[k]);
        float sper = 0.f, sval = 0.f;
#pragma unroll
        for (int r = 0; r < ROWS_E; ++r) {
            int i = i0 + r;
            if (i < F) {
                float rowRank = red[0][r*2+0] + red[1][r*2+0] + red[2][r*2+0] + red[3][r*2+0];
                float rowDist = red[0][r*2+1] + red[1][r*2+1] + red[2][r*2+1] + red[3][r*2+1];
                float rkv = rowRank + rank2[i];
                float dtv = (rowDist + dist2[i]) * APE_LN2;
                bool valid = (gmax > logits[i] - 1.0f) || (cnt2[i] > 0.f);
                if (valid) {
                    sper += dtv * ious[i] / rkv;
                    sval += 1.f;
                }
            }
        }
        ST_AGENT(&pp[blockIdx.x], sper);   // sc0 sc1: bypass L2, land at LLC
        ST_AGENT(&pv[blockIdx.x], sval);
        asm volatile("s_waitcnt vmcnt(0)" ::: "memory");  // stores complete at LLC
        int old = __hip_atomic_fetch_add(ctr, 1, __ATOMIC_RELAXED,
                                         __HIP_MEMORY_SCOPE_AGENT);
        lastFlag = (old == EB - 1) ? 1 : 0;
    }
    __syncthreads();
    if (!lastFlag) return;

    // last block: deterministic fixed-order reduce of the partials
    float sp = 0.f, sv = 0.f;
    for (int k = tid; k < EB; k += TPB) {
        sp += LD_AGENT(&pp[k]);
        sv += LD_AGENT(&pv[k]);
    }
    __shared__ float rp[4], rv[4];
    for (int off = 32; off > 0; off >>= 1) {
        sp += __shfl_down(sp, off);
        sv += __shfl_down(sv, off);
    }
    if (lane == 0) { rp[wid] = sp; rv[wid] = sv; }
    __syncthreads();
    if (tid == 0) {
        float p = rp[0] + rp[1] + rp[2] + rp[3];
        float v = rv[0] + rv[1] + rv[2] + rv[3];
        out[0] = p / fmaxf(v, 1.f) / APE_LAMB;
    }
}

extern "C" void kernel_launch(void* const* d_in, const int* in_sizes, int n_in,
                              void* d_out, int out_size, void* d_ws, size_t ws_size,
                              hipStream_t stream) {
    const float* logits = (const float*)d_in[0];
    const float* ious   = (const float*)d_in[2];
    const int N = in_sizes[0];
    const int F = in_sizes[2];
    const int M = N - F;

    const int FB = (F + ROWS_B - 1) / ROWS_B;
    const int EB = (F + ROWS_E - 1) / ROWS_E;

    float2* gH   = (float2*)d_ws;            // [NB][B_BINS] (count, m1)
    float* bmaxA = (float*)(gH + NB * B_BINS); // [NB]
    float* dist2 = bmaxA + NB;               // [F]
    float* rank2 = dist2 + F;                // [F]
    float* cnt2  = rank2 + F;                // [F]
    float* pp    = cnt2 + F;                 // [EB]
    float* pv    = pp + EB;                  // [EB]
    int*   ctr   = (int*)(pv + EB);          // [1]

    int chunkH = ((M + NB - 1) / NB + 3) & ~3;
    if (chunkH < 4) chunkH = 4;

    ape_phase1<<<NB + FB, TPB, 0, stream>>>(logits, ious, F, M, chunkH,
                                            gH, bmaxA, dist2, rank2, cnt2, ctr);
    ape_phase2<<<EB, TPB, 0, stream>>>(logits, ious, F, EB, gH, bmaxA,
                                       dist2, rank2, cnt2, pp, pv, ctr,
                                       (float*)d_out);
}